// Round 3
// baseline (1191.033 us; speedup 1.0000x reference)
//
#include <hip/hip_runtime.h>
#include <math.h>

#define NGENES 19836
#define BATCH 8
#define DIN 11
#define DH 64
#define NNODES (BATCH * NGENES)        /* 158688 */
#define NEDGES (NNODES * 16)           /* 2539008 */
#define NDH (NNODES * DH)              /* 10156032 */
#define NGRP (NNODES / 4)              /* 39672 */

#define SCAN_CHUNK 1024
#define NSBLK ((NNODES + SCAN_CHUNK - 1) / SCAN_CHUNK)  /* 155 */

/* output layout (floats): preds[8], w[NNODES], sae_loss[1], dec[NNODES*64] */
#define OUT_PREDS 0
#define OUT_W 8
#define OUT_SAE (8 + NNODES)
#define OUT_DEC (9 + NNODES)

__device__ __forceinline__ float gelu_f(float x) {
    return 0.5f * x * (1.0f + erff(x * 0.70710678118654752f));
}

__device__ __forceinline__ float bcast(float v, int lane) {
    return __int_as_float(__builtin_amdgcn_readlane(__float_as_int(v), lane));
}

__device__ __forceinline__ float wave_sum(float v) {
    #pragma unroll
    for (int o = 32; o; o >>= 1) v += __shfl_xor(v, o, 64);
    return v;
}

/* K1: h = gelu(x @ enc_W.T + enc_b) + gene_emb[gene] */
__global__ void k_encoder(const float* __restrict__ x, const float* __restrict__ encW,
                          const float* __restrict__ encB, const float* __restrict__ gemb,
                          float* __restrict__ h) {
    int lane = threadIdx.x & 63;
    int wid = (blockIdx.x * blockDim.x + threadIdx.x) >> 6;
    int tw = (gridDim.x * blockDim.x) >> 6;
    int chunk = (NNODES + tw - 1) / tw;
    int start = wid * chunk;
    int end = min(start + chunk, NNODES);
    float wreg[DIN];
    #pragma unroll
    for (int k = 0; k < DIN; ++k) wreg[k] = encW[lane * DIN + k];
    float bias = encB[lane];
    for (int node = start; node < end; ++node) {
        const float* xr = x + (size_t)node * DIN;
        float acc = bias;
        #pragma unroll
        for (int k = 0; k < DIN; ++k) acc = fmaf(xr[k], wreg[k], acc);
        int gene = node % NGENES;
        h[(size_t)node * DH + lane] = gelu_f(acc) + gemb[(size_t)gene * DH + lane];
    }
}

/* CSR build: histogram of dst */
__global__ void k_hist(const int* __restrict__ dst, int* __restrict__ counts) {
    int i = blockIdx.x * blockDim.x + threadIdx.x;
    int stride = gridDim.x * blockDim.x;
    for (int e = i; e < NEDGES; e += stride)
        atomicAdd(&counts[dst[e]], 1);
}

/* scan pass 1: per-block sums (block covers SCAN_CHUNK counts) */
__global__ void k_scan1(const int* __restrict__ counts, int* __restrict__ bsum) {
    __shared__ int red[256];
    int base = blockIdx.x * SCAN_CHUNK + threadIdx.x * 4;
    int s = 0;
    #pragma unroll
    for (int i = 0; i < 4; ++i) {
        int n = base + i;
        if (n < NNODES) s += counts[n];
    }
    red[threadIdx.x] = s;
    __syncthreads();
    for (int o = 128; o; o >>= 1) {
        if (threadIdx.x < o) red[threadIdx.x] += red[threadIdx.x + o];
        __syncthreads();
    }
    if (threadIdx.x == 0) bsum[blockIdx.x] = red[0];
}

/* scan pass 2: exclusive scan of block sums — single-block LDS scan */
__global__ void k_scan2(const int* __restrict__ bsum, int* __restrict__ boff) {
    __shared__ int red[256];
    int t = threadIdx.x;
    int v = (t < NSBLK) ? bsum[t] : 0;
    red[t] = v;
    __syncthreads();
    for (int o = 1; o < 256; o <<= 1) {
        int u = (t >= o) ? red[t - o] : 0;
        __syncthreads();
        red[t] += u;
        __syncthreads();
    }
    if (t < NSBLK) boff[t] = red[t] - v;
}

/* scan pass 3: intra-block exclusive scan -> offsets, cursor */
__global__ void k_scan3(const int* __restrict__ counts, const int* __restrict__ boff,
                        int* __restrict__ offsets, int* __restrict__ cursor) {
    __shared__ int red[256];
    int t = threadIdx.x;
    int base = blockIdx.x * SCAN_CHUNK + t * 4;
    int c[4];
    int s = 0;
    #pragma unroll
    for (int i = 0; i < 4; ++i) {
        int n = base + i;
        c[i] = (n < NNODES) ? counts[n] : 0;
        s += c[i];
    }
    red[t] = s;
    __syncthreads();
    for (int o = 1; o < 256; o <<= 1) {
        int v = (t >= o) ? red[t - o] : 0;
        __syncthreads();
        red[t] += v;
        __syncthreads();
    }
    int excl = red[t] - s + boff[blockIdx.x];
    #pragma unroll
    for (int i = 0; i < 4; ++i) {
        int n = base + i;
        if (n < NNODES) { offsets[n] = excl; cursor[n] = excl; }
        excl += c[i];
    }
}

/* scatter edges into CSR; store LOCAL src id (src and dst share a graph) */
__global__ void k_scatter(const int* __restrict__ src, const int* __restrict__ dst,
                          int* __restrict__ cursor, unsigned short* __restrict__ csr) {
    int i = blockIdx.x * blockDim.x + threadIdx.x;
    int stride = gridDim.x * blockDim.x;
    for (int e = i; e < NEDGES; e += stride) {
        int p = atomicAdd(&cursor[dst[e]], 1);
        csr[p] = (unsigned short)(src[e] % NGENES);
    }
}

/* fused: agg gather + GIN matmul + BN stats. wave per node, strided for L2 locality */
__global__ void k_aggin(const float* __restrict__ h, const int* __restrict__ offsets,
                        const int* __restrict__ counts, const unsigned short* __restrict__ csr,
                        const float* __restrict__ ginW, float* __restrict__ h2,
                        float* __restrict__ stats) {
    int lane = threadIdx.x & 63;
    int wid = (blockIdx.x * blockDim.x + threadIdx.x) >> 6;
    int tw = (gridDim.x * blockDim.x) >> 6;
    float wr[DH];
    #pragma unroll
    for (int k = 0; k < DH; ++k) wr[k] = ginW[lane * DH + k];
    float s1 = 0.f, s2 = 0.f;
    for (int node = wid; node < NNODES; node += tw) {
        int gbase = (node / NGENES) * NGENES;
        float a[8];
        a[0] = h[(size_t)node * DH + lane];
        #pragma unroll
        for (int i = 1; i < 8; ++i) a[i] = 0.f;
        int start = offsets[node];
        int cnt = counts[node];
        for (int e0 = 0; e0 < cnt; e0 += 64) {
            int nn = min(64, cnt - e0);
            int iv = (lane < nn) ? (int)csr[start + e0 + lane] : 0;
            int j = 0;
            for (; j + 7 < nn; j += 8) {
                #pragma unroll
                for (int u = 0; u < 8; ++u) {
                    int v = gbase + __shfl(iv, j + u, 64);
                    a[u] += h[(size_t)v * DH + lane];
                }
            }
            for (; j < nn; ++j)
                a[0] += h[(size_t)(gbase + __shfl(iv, j, 64)) * DH + lane];
        }
        float tval = ((a[0] + a[1]) + (a[2] + a[3])) + ((a[4] + a[5]) + (a[6] + a[7]));
        float m0 = 0.f, m1 = 0.f, m2 = 0.f, m3 = 0.f;
        #pragma unroll
        for (int k = 0; k < DH; k += 4) {
            m0 = fmaf(wr[k], bcast(tval, k), m0);
            m1 = fmaf(wr[k + 1], bcast(tval, k + 1), m1);
            m2 = fmaf(wr[k + 2], bcast(tval, k + 2), m2);
            m3 = fmaf(wr[k + 3], bcast(tval, k + 3), m3);
        }
        float outv = (m0 + m1) + (m2 + m3);
        h2[(size_t)node * DH + lane] = outv;
        s1 += outv;
        s2 += outv * outv;
    }
    __shared__ float red[2][256];
    red[0][threadIdx.x] = s1;
    red[1][threadIdx.x] = s2;
    __syncthreads();
    if (threadIdx.x < 64) {
        float t1 = red[0][threadIdx.x] + red[0][threadIdx.x + 64] + red[0][threadIdx.x + 128] + red[0][threadIdx.x + 192];
        float t2 = red[1][threadIdx.x] + red[1][threadIdx.x + 64] + red[1][threadIdx.x + 128] + red[1][threadIdx.x + 192];
        atomicAdd(&stats[threadIdx.x], t1);
        atomicAdd(&stats[64 + threadIdx.x], t2);
    }
}

/* bn scale/shift from stats + collapsed key/query vector KQ, qb */
__global__ void k_bnparams(const float* __restrict__ stats, const float* __restrict__ bnw,
                           const float* __restrict__ bnb, const float* __restrict__ keyW,
                           const float* __restrict__ keyB, const float* __restrict__ qw,
                           float* __restrict__ bnp) {
    int d = threadIdx.x;
    float inv_n = 1.0f / (float)NNODES;
    float mu = stats[d] * inv_n;
    float var = stats[64 + d] * inv_n - mu * mu;
    float sc = bnw[d] * rsqrtf(var + 1e-5f);
    bnp[d] = sc;
    bnp[64 + d] = bnb[d] - mu * sc;
    /* KQ[k] = sum_d qw[d] * keyW[d][k] ; thread d=k computes column k */
    float kq0 = 0.f, kq1 = 0.f;
    #pragma unroll
    for (int j = 0; j < DH; j += 2) {
        kq0 = fmaf(qw[j], keyW[j * DH + d], kq0);
        kq1 = fmaf(qw[j + 1], keyW[(j + 1) * DH + d], kq1);
    }
    bnp[128 + d] = kq0 + kq1;
    float qb = wave_sum(qw[d] * keyB[d]);
    if (d == 0) bnp[192] = qb;
}

/* h3 = gelu(bn(h2)); wq = sigmoid(h3.KQ + qb); z = (h3@valW.T+vb)*wq  (in-place) */
__global__ void k_attn(float* __restrict__ h2, const float* __restrict__ bnp,
                       const float* __restrict__ valW, const float* __restrict__ valB,
                       float* __restrict__ wout) {
    int lane = threadIdx.x & 63;
    int wid = (blockIdx.x * blockDim.x + threadIdx.x) >> 6;
    int tw = (gridDim.x * blockDim.x) >> 6;
    int chunk = (NGRP + tw - 1) / tw;
    int gs = wid * chunk;
    int ge = min(gs + chunk, NGRP);
    float vw[DH];
    #pragma unroll
    for (int k = 0; k < DH; ++k) vw[k] = valW[lane * DH + k];
    float vb = valB[lane], sc = bnp[lane], sh = bnp[64 + lane], kq = bnp[128 + lane];
    float qb = bnp[192];
    for (int g = gs; g < ge; ++g) {
        int node = g * 4;
        float h3[4], p[4];
        #pragma unroll
        for (int i = 0; i < 4; ++i) {
            float hv = h2[(size_t)(node + i) * DH + lane];
            h3[i] = gelu_f(fmaf(hv, sc, sh));
            p[i] = h3[i] * kq;
        }
        #pragma unroll
        for (int o = 32; o; o >>= 1) {
            #pragma unroll
            for (int i = 0; i < 4; ++i) p[i] += __shfl_xor(p[i], o, 64);
        }
        float wq[4];
        #pragma unroll
        for (int i = 0; i < 4; ++i) wq[i] = 1.0f / (1.0f + expf(-(p[i] + qb)));
        float a[4];
        #pragma unroll
        for (int i = 0; i < 4; ++i) a[i] = 0.f;
        #pragma unroll
        for (int k = 0; k < DH; ++k) {
            #pragma unroll
            for (int i = 0; i < 4; ++i) a[i] = fmaf(vw[k], bcast(h3[i], k), a[i]);
        }
        #pragma unroll
        for (int i = 0; i < 4; ++i)
            h2[(size_t)(node + i) * DH + lane] = (a[i] + vb) * wq[i];
        if (lane == 0) {
            wout[node] = wq[0]; wout[node + 1] = wq[1];
            wout[node + 2] = wq[2]; wout[node + 3] = wq[3];
        }
    }
}

/* enc = relu(z@encW.T+eb); dec = enc@decW.T+db; loss partials; g_h += dec*wq */
__global__ void k_sae(const float* __restrict__ zbuf, const float* __restrict__ encW,
                      const float* __restrict__ encB, const float* __restrict__ decW,
                      const float* __restrict__ decB, const float* __restrict__ wout,
                      float* __restrict__ decout, float* __restrict__ g_h,
                      float* __restrict__ loss) {
    int lane = threadIdx.x & 63;
    int wid = (blockIdx.x * blockDim.x + threadIdx.x) >> 6;
    int tw = (gridDim.x * blockDim.x) >> 6;
    int chunk = (NGRP + tw - 1) / tw;
    int gs = wid * chunk;
    int ge = min(gs + chunk, NGRP);
    float ew[DH], dw[DH];
    #pragma unroll
    for (int k = 0; k < DH; ++k) {
        ew[k] = encW[lane * DH + k];
        dw[k] = decW[lane * DH + k];
    }
    float eb = encB[lane], db = decB[lane];
    float sq = 0.f, l1 = 0.f, gacc = 0.f;
    int cur_g = (gs < NGRP) ? (gs * 4) / NGENES : 0;
    for (int g = gs; g < ge; ++g) {
        int node = g * 4;                      /* NGENES%4==0: group never straddles graphs */
        int gg = node / NGENES;
        if (gg != cur_g) {
            atomicAdd(&g_h[cur_g * DH + lane], gacc);
            gacc = 0.f;
            cur_g = gg;
        }
        float z[4], e[4], enc[4], d[4];
        #pragma unroll
        for (int i = 0; i < 4; ++i) {
            z[i] = zbuf[(size_t)(node + i) * DH + lane];
            e[i] = 0.f;
        }
        #pragma unroll
        for (int k = 0; k < DH; ++k) {
            #pragma unroll
            for (int i = 0; i < 4; ++i) e[i] = fmaf(ew[k], bcast(z[i], k), e[i]);
        }
        #pragma unroll
        for (int i = 0; i < 4; ++i) {
            enc[i] = fmaxf(e[i] + eb, 0.0f);
            d[i] = 0.f;
        }
        #pragma unroll
        for (int k = 0; k < DH; ++k) {
            #pragma unroll
            for (int i = 0; i < 4; ++i) d[i] = fmaf(dw[k], bcast(enc[i], k), d[i]);
        }
        #pragma unroll
        for (int i = 0; i < 4; ++i) {
            float dec = d[i] + db;
            float wq = wout[node + i];
            decout[(size_t)(node + i) * DH + lane] = dec;
            float diff = dec - z[i];
            sq = fmaf(diff, diff, sq);
            l1 += fabsf(enc[i]);
            gacc = fmaf(dec, wq, gacc);
        }
    }
    if (gs < ge) atomicAdd(&g_h[cur_g * DH + lane], gacc);
    sq = wave_sum(sq);
    l1 = wave_sum(l1);
    if (lane == 0) {
        atomicAdd(&loss[0], sq);
        atomicAdd(&loss[1], l1);
    }
}

/* preds = gelu(g_h@W1.T+b1)@W2.T + b2; sae_loss final */
__global__ void k_pred(const float* __restrict__ g_h, const float* __restrict__ W1,
                       const float* __restrict__ b1, const float* __restrict__ W2,
                       const float* __restrict__ b2, const float* __restrict__ loss,
                       float* __restrict__ out) {
    int lane = threadIdx.x;
    float w1[DH];
    #pragma unroll
    for (int k = 0; k < DH; ++k) w1[k] = W1[lane * DH + k];
    float bb = b1[lane], w2 = W2[lane];
    for (int g = 0; g < BATCH; ++g) {
        float gh = g_h[g * DH + lane];
        float a0 = 0.f, a1 = 0.f;
        #pragma unroll
        for (int k = 0; k < DH; k += 2) {
            a0 = fmaf(w1[k], bcast(gh, k), a0);
            a1 = fmaf(w1[k + 1], bcast(gh, k + 1), a1);
        }
        float t = gelu_f(a0 + a1 + bb);
        float p = wave_sum(t * w2);
        if (lane == 0) out[OUT_PREDS + g] = p + b2[0];
    }
    if (lane == 0) out[OUT_SAE] = (loss[0] + loss[1]) * (1.0f / ((float)NNODES * (float)DH));
}

extern "C" void kernel_launch(void* const* d_in, const int* in_sizes, int n_in,
                              void* d_out, int out_size, void* d_ws, size_t ws_size,
                              hipStream_t stream) {
    const float* x    = (const float*)d_in[0];
    const int* src    = (const int*)d_in[1];
    const int* dst    = (const int*)d_in[2];
    const float* encW = (const float*)d_in[3];
    const float* encB = (const float*)d_in[4];
    const float* gemb = (const float*)d_in[5];
    const float* ginW = (const float*)d_in[6];
    const float* bnw  = (const float*)d_in[7];
    const float* bnb  = (const float*)d_in[8];
    const float* keyW = (const float*)d_in[9];
    const float* keyB = (const float*)d_in[10];
    const float* qw   = (const float*)d_in[11];
    const float* valW = (const float*)d_in[12];
    const float* valB = (const float*)d_in[13];
    const float* saeEncW = (const float*)d_in[14];
    const float* saeEncB = (const float*)d_in[15];
    const float* saeDecW = (const float*)d_in[16];
    const float* saeDecB = (const float*)d_in[17];
    const float* pW1  = (const float*)d_in[18];
    const float* pb1  = (const float*)d_in[19];
    const float* pW2  = (const float*)d_in[20];
    const float* pb2  = (const float*)d_in[21];

    float* out = (float*)d_out;
    float* ws = (float*)d_ws;

    /* ws layout */
    int*   counts  = (int*)ws;                     /* NNODES */
    float* stats   = ws + NNODES;                  /* 128 */
    float* g_h     = stats + 128;                  /* 512 */
    float* loss    = g_h + 512;                    /* 2 */
    float* bnp     = loss + 2;                     /* 256: sc, sh, KQ, qb */
    int*   offsets = (int*)(bnp + 256);            /* NNODES */
    int*   cursor  = offsets + NNODES;             /* NNODES */
    unsigned short* csr = (unsigned short*)(cursor + NNODES); /* NEDGES u16 */
    int*   bsum    = (int*)(csr + NEDGES);         /* 256 */
    int*   boff    = bsum + 256;                   /* 256 */
    float* h2      = (float*)(boff + 256);         /* NDH */

    float* h    = out + OUT_DEC;   /* encoder output lives in dec region until k_sae */
    float* wout = out + OUT_W;

    /* zero counts + stats + g_h + loss */
    hipMemsetAsync(d_ws, 0, (size_t)(NNODES + 642) * sizeof(float), stream);

    k_encoder<<<2048, 256, 0, stream>>>(x, encW, encB, gemb, h);
    k_hist<<<2048, 256, 0, stream>>>(dst, counts);
    k_scan1<<<NSBLK, 256, 0, stream>>>(counts, bsum);
    k_scan2<<<1, 256, 0, stream>>>(bsum, boff);
    k_scan3<<<NSBLK, 256, 0, stream>>>(counts, boff, offsets, cursor);
    k_scatter<<<2048, 256, 0, stream>>>(src, dst, cursor, csr);
    k_aggin<<<2048, 256, 0, stream>>>(h, offsets, counts, csr, ginW, h2, stats);
    k_bnparams<<<1, 64, 0, stream>>>(stats, bnw, bnb, keyW, keyB, qw, bnp);
    k_attn<<<2048, 256, 0, stream>>>(h2, bnp, valW, valB, wout);
    k_sae<<<2048, 256, 0, stream>>>(h2, saeEncW, saeEncB, saeDecW, saeDecB, wout, h, g_h, loss);
    k_pred<<<1, 64, 0, stream>>>(g_h, pW1, pb1, pW2, pb2, loss, out);
}

// Round 4
// 898.859 us; speedup vs baseline: 1.3251x; 1.3251x over previous
//
#include <hip/hip_runtime.h>
#include <math.h>

#define NGENES 19836
#define BATCH 8
#define DIN 11
#define DH 64
#define NNODES (BATCH * NGENES)        /* 158688 */
#define NEDGES (NNODES * 16)           /* 2539008 */
#define NDH (NNODES * DH)              /* 10156032 */
#define NGRP (NNODES / 4)              /* 39672 */

#define SCAN_CHUNK 1024
#define NSBLK ((NNODES + SCAN_CHUNK - 1) / SCAN_CHUNK)  /* 155 */

/* output layout (floats): preds[8], w[NNODES], sae_loss[1], dec[NNODES*64] */
#define OUT_PREDS 0
#define OUT_W 8
#define OUT_SAE (8 + NNODES)
#define OUT_DEC (9 + NNODES)

__device__ __forceinline__ float gelu_f(float x) {
    return 0.5f * x * (1.0f + erff(x * 0.70710678118654752f));
}

__device__ __forceinline__ float bcast(float v, int lane) {
    return __int_as_float(__builtin_amdgcn_readlane(__float_as_int(v), lane));
}

__device__ __forceinline__ float wave_sum(float v) {
    #pragma unroll
    for (int o = 32; o; o >>= 1) v += __shfl_xor(v, o, 64);
    return v;
}

/* K1: h = gelu(x @ enc_W.T + enc_b) + gene_emb[gene] */
__global__ void k_encoder(const float* __restrict__ x, const float* __restrict__ encW,
                          const float* __restrict__ encB, const float* __restrict__ gemb,
                          float* __restrict__ h) {
    int lane = threadIdx.x & 63;
    int wid = (blockIdx.x * blockDim.x + threadIdx.x) >> 6;
    int tw = (gridDim.x * blockDim.x) >> 6;
    int chunk = (NNODES + tw - 1) / tw;
    int start = wid * chunk;
    int end = min(start + chunk, NNODES);
    float wreg[DIN];
    #pragma unroll
    for (int k = 0; k < DIN; ++k) wreg[k] = encW[lane * DIN + k];
    float bias = encB[lane];
    for (int node = start; node < end; ++node) {
        const float* xr = x + (size_t)node * DIN;
        float acc = bias;
        #pragma unroll
        for (int k = 0; k < DIN; ++k) acc = fmaf(xr[k], wreg[k], acc);
        int gene = node % NGENES;
        h[(size_t)node * DH + lane] = gelu_f(acc) + gemb[(size_t)gene * DH + lane];
    }
}

/* CSR build: histogram of dst */
__global__ void k_hist(const int* __restrict__ dst, int* __restrict__ counts) {
    int i = blockIdx.x * blockDim.x + threadIdx.x;
    int stride = gridDim.x * blockDim.x;
    for (int e = i; e < NEDGES; e += stride)
        atomicAdd(&counts[dst[e]], 1);
}

/* scan pass 1: per-block sums (block covers SCAN_CHUNK counts) */
__global__ void k_scan1(const int* __restrict__ counts, int* __restrict__ bsum) {
    __shared__ int red[256];
    int base = blockIdx.x * SCAN_CHUNK + threadIdx.x * 4;
    int s = 0;
    #pragma unroll
    for (int i = 0; i < 4; ++i) {
        int n = base + i;
        if (n < NNODES) s += counts[n];
    }
    red[threadIdx.x] = s;
    __syncthreads();
    for (int o = 128; o; o >>= 1) {
        if (threadIdx.x < o) red[threadIdx.x] += red[threadIdx.x + o];
        __syncthreads();
    }
    if (threadIdx.x == 0) bsum[blockIdx.x] = red[0];
}

/* scan pass 2: exclusive scan of block sums — single-block LDS scan */
__global__ void k_scan2(const int* __restrict__ bsum, int* __restrict__ boff) {
    __shared__ int red[256];
    int t = threadIdx.x;
    int v = (t < NSBLK) ? bsum[t] : 0;
    red[t] = v;
    __syncthreads();
    for (int o = 1; o < 256; o <<= 1) {
        int u = (t >= o) ? red[t - o] : 0;
        __syncthreads();
        red[t] += u;
        __syncthreads();
    }
    if (t < NSBLK) boff[t] = red[t] - v;
}

/* scan pass 3: intra-block exclusive scan -> offsets, cursor */
__global__ void k_scan3(const int* __restrict__ counts, const int* __restrict__ boff,
                        int* __restrict__ offsets, int* __restrict__ cursor) {
    __shared__ int red[256];
    int t = threadIdx.x;
    int base = blockIdx.x * SCAN_CHUNK + t * 4;
    int c[4];
    int s = 0;
    #pragma unroll
    for (int i = 0; i < 4; ++i) {
        int n = base + i;
        c[i] = (n < NNODES) ? counts[n] : 0;
        s += c[i];
    }
    red[t] = s;
    __syncthreads();
    for (int o = 1; o < 256; o <<= 1) {
        int v = (t >= o) ? red[t - o] : 0;
        __syncthreads();
        red[t] += v;
        __syncthreads();
    }
    int excl = red[t] - s + boff[blockIdx.x];
    #pragma unroll
    for (int i = 0; i < 4; ++i) {
        int n = base + i;
        if (n < NNODES) { offsets[n] = excl; cursor[n] = excl; }
        excl += c[i];
    }
}

/* scatter edges into CSR; store LOCAL src id (src and dst share a graph) */
__global__ void k_scatter(const int* __restrict__ src, const int* __restrict__ dst,
                          int* __restrict__ cursor, unsigned short* __restrict__ csr) {
    int i = blockIdx.x * blockDim.x + threadIdx.x;
    int stride = gridDim.x * blockDim.x;
    for (int e = i; e < NEDGES; e += stride) {
        int p = atomicAdd(&cursor[dst[e]], 1);
        csr[p] = (unsigned short)(src[e] % NGENES);
    }
}

/* fused: agg gather + GIN matmul + BN stats. wave per node, strided for L2 locality */
__global__ void __launch_bounds__(256, 3)
k_aggin(const float* __restrict__ h, const int* __restrict__ offsets,
        const int* __restrict__ counts, const unsigned short* __restrict__ csr,
        const float* __restrict__ ginW, float* __restrict__ h2,
        float* __restrict__ stats) {
    int lane = threadIdx.x & 63;
    int wid = (blockIdx.x * blockDim.x + threadIdx.x) >> 6;
    int tw = (gridDim.x * blockDim.x) >> 6;
    float wr[DH];
    #pragma unroll
    for (int k = 0; k < DH; ++k) wr[k] = ginW[lane * DH + k];
    float s1 = 0.f, s2 = 0.f;
    for (int node = wid; node < NNODES; node += tw) {
        int gbase = (node / NGENES) * NGENES;
        float a[8];
        a[0] = h[(size_t)node * DH + lane];
        #pragma unroll
        for (int i = 1; i < 8; ++i) a[i] = 0.f;
        int start = offsets[node];
        int cnt = counts[node];
        for (int e0 = 0; e0 < cnt; e0 += 64) {
            int nn = min(64, cnt - e0);
            int iv = (lane < nn) ? (int)csr[start + e0 + lane] : 0;
            int j = 0;
            for (; j + 7 < nn; j += 8) {
                #pragma unroll
                for (int u = 0; u < 8; ++u) {
                    int v = gbase + __shfl(iv, j + u, 64);
                    a[u] += h[(size_t)v * DH + lane];
                }
            }
            for (; j < nn; ++j)
                a[0] += h[(size_t)(gbase + __shfl(iv, j, 64)) * DH + lane];
        }
        float tval = ((a[0] + a[1]) + (a[2] + a[3])) + ((a[4] + a[5]) + (a[6] + a[7]));
        float m0 = 0.f, m1 = 0.f, m2 = 0.f, m3 = 0.f;
        #pragma unroll
        for (int k = 0; k < DH; k += 4) {
            m0 = fmaf(wr[k], bcast(tval, k), m0);
            m1 = fmaf(wr[k + 1], bcast(tval, k + 1), m1);
            m2 = fmaf(wr[k + 2], bcast(tval, k + 2), m2);
            m3 = fmaf(wr[k + 3], bcast(tval, k + 3), m3);
        }
        float outv = (m0 + m1) + (m2 + m3);
        h2[(size_t)node * DH + lane] = outv;
        s1 += outv;
        s2 += outv * outv;
    }
    __shared__ float red[2][256];
    red[0][threadIdx.x] = s1;
    red[1][threadIdx.x] = s2;
    __syncthreads();
    if (threadIdx.x < 64) {
        float t1 = red[0][threadIdx.x] + red[0][threadIdx.x + 64] + red[0][threadIdx.x + 128] + red[0][threadIdx.x + 192];
        float t2 = red[1][threadIdx.x] + red[1][threadIdx.x + 64] + red[1][threadIdx.x + 128] + red[1][threadIdx.x + 192];
        atomicAdd(&stats[threadIdx.x], t1);
        atomicAdd(&stats[64 + threadIdx.x], t2);
    }
}

/* bn scale/shift from stats + collapsed key/query vector KQ, qb */
__global__ void k_bnparams(const float* __restrict__ stats, const float* __restrict__ bnw,
                           const float* __restrict__ bnb, const float* __restrict__ keyW,
                           const float* __restrict__ keyB, const float* __restrict__ qw,
                           float* __restrict__ bnp) {
    int d = threadIdx.x;
    float inv_n = 1.0f / (float)NNODES;
    float mu = stats[d] * inv_n;
    float var = stats[64 + d] * inv_n - mu * mu;
    float sc = bnw[d] * rsqrtf(var + 1e-5f);
    bnp[d] = sc;
    bnp[64 + d] = bnb[d] - mu * sc;
    /* KQ[k] = sum_d qw[d] * keyW[d][k] ; thread d=k computes column k */
    float kq0 = 0.f, kq1 = 0.f;
    #pragma unroll
    for (int j = 0; j < DH; j += 2) {
        kq0 = fmaf(qw[j], keyW[j * DH + d], kq0);
        kq1 = fmaf(qw[j + 1], keyW[(j + 1) * DH + d], kq1);
    }
    bnp[128 + d] = kq0 + kq1;
    float qb = wave_sum(qw[d] * keyB[d]);
    if (d == 0) bnp[192] = qb;
}

/* h3 = gelu(bn(h2)); wq = sigmoid(h3.KQ + qb); z = (h3@valW.T+vb)*wq  (in-place) */
__global__ void __launch_bounds__(256, 3)
k_attn(float* __restrict__ h2, const float* __restrict__ bnp,
       const float* __restrict__ valW, const float* __restrict__ valB,
       float* __restrict__ wout) {
    int lane = threadIdx.x & 63;
    int wid = (blockIdx.x * blockDim.x + threadIdx.x) >> 6;
    int tw = (gridDim.x * blockDim.x) >> 6;
    int chunk = (NGRP + tw - 1) / tw;
    int gs = wid * chunk;
    int ge = min(gs + chunk, NGRP);
    float vw[DH];
    #pragma unroll
    for (int k = 0; k < DH; ++k) vw[k] = valW[lane * DH + k];
    float vb = valB[lane], sc = bnp[lane], sh = bnp[64 + lane], kq = bnp[128 + lane];
    float qb = bnp[192];
    for (int g = gs; g < ge; ++g) {
        int node = g * 4;
        float h3[4], p[4];
        #pragma unroll
        for (int i = 0; i < 4; ++i) {
            float hv = h2[(size_t)(node + i) * DH + lane];
            h3[i] = gelu_f(fmaf(hv, sc, sh));
            p[i] = h3[i] * kq;
        }
        #pragma unroll
        for (int o = 32; o; o >>= 1) {
            #pragma unroll
            for (int i = 0; i < 4; ++i) p[i] += __shfl_xor(p[i], o, 64);
        }
        float wq[4];
        #pragma unroll
        for (int i = 0; i < 4; ++i) wq[i] = 1.0f / (1.0f + expf(-(p[i] + qb)));
        float a[4];
        #pragma unroll
        for (int i = 0; i < 4; ++i) a[i] = 0.f;
        #pragma unroll
        for (int k = 0; k < DH; ++k) {
            #pragma unroll
            for (int i = 0; i < 4; ++i) a[i] = fmaf(vw[k], bcast(h3[i], k), a[i]);
        }
        #pragma unroll
        for (int i = 0; i < 4; ++i)
            h2[(size_t)(node + i) * DH + lane] = (a[i] + vb) * wq[i];
        if (lane == 0) {
            wout[node] = wq[0]; wout[node + 1] = wq[1];
            wout[node + 2] = wq[2]; wout[node + 3] = wq[3];
        }
    }
}

/* enc = relu(z@encW.T+eb); dec = enc@decW.T+db; loss partials; g_h += dec*wq */
__global__ void __launch_bounds__(256, 2)
k_sae(const float* __restrict__ zbuf, const float* __restrict__ encW,
      const float* __restrict__ encB, const float* __restrict__ decW,
      const float* __restrict__ decB, const float* __restrict__ wout,
      float* __restrict__ decout, float* __restrict__ g_h,
      float* __restrict__ loss) {
    int lane = threadIdx.x & 63;
    int wid = (blockIdx.x * blockDim.x + threadIdx.x) >> 6;
    int tw = (gridDim.x * blockDim.x) >> 6;
    int chunk = (NGRP + tw - 1) / tw;
    int gs = wid * chunk;
    int ge = min(gs + chunk, NGRP);
    float ew[DH], dw[DH];
    #pragma unroll
    for (int k = 0; k < DH; ++k) {
        ew[k] = encW[lane * DH + k];
        dw[k] = decW[lane * DH + k];
    }
    float eb = encB[lane], db = decB[lane];
    float sq = 0.f, l1 = 0.f, gacc = 0.f;
    int cur_g = (gs < NGRP) ? (gs * 4) / NGENES : 0;
    for (int g = gs; g < ge; ++g) {
        int node = g * 4;                      /* NGENES%4==0: group never straddles graphs */
        int gg = node / NGENES;
        if (gg != cur_g) {
            atomicAdd(&g_h[cur_g * DH + lane], gacc);
            gacc = 0.f;
            cur_g = gg;
        }
        float z[4], e[4], enc[4], d[4];
        #pragma unroll
        for (int i = 0; i < 4; ++i) {
            z[i] = zbuf[(size_t)(node + i) * DH + lane];
            e[i] = 0.f;
        }
        #pragma unroll
        for (int k = 0; k < DH; ++k) {
            #pragma unroll
            for (int i = 0; i < 4; ++i) e[i] = fmaf(ew[k], bcast(z[i], k), e[i]);
        }
        #pragma unroll
        for (int i = 0; i < 4; ++i) {
            enc[i] = fmaxf(e[i] + eb, 0.0f);
            d[i] = 0.f;
        }
        #pragma unroll
        for (int k = 0; k < DH; ++k) {
            #pragma unroll
            for (int i = 0; i < 4; ++i) d[i] = fmaf(dw[k], bcast(enc[i], k), d[i]);
        }
        #pragma unroll
        for (int i = 0; i < 4; ++i) {
            float dec = d[i] + db;
            float wq = wout[node + i];
            decout[(size_t)(node + i) * DH + lane] = dec;
            float diff = dec - z[i];
            sq = fmaf(diff, diff, sq);
            l1 += fabsf(enc[i]);
            gacc = fmaf(dec, wq, gacc);
        }
    }
    if (gs < ge) atomicAdd(&g_h[cur_g * DH + lane], gacc);
    sq = wave_sum(sq);
    l1 = wave_sum(l1);
    if (lane == 0) {
        atomicAdd(&loss[0], sq);
        atomicAdd(&loss[1], l1);
    }
}

/* preds = gelu(g_h@W1.T+b1)@W2.T + b2; sae_loss final */
__global__ void k_pred(const float* __restrict__ g_h, const float* __restrict__ W1,
                       const float* __restrict__ b1, const float* __restrict__ W2,
                       const float* __restrict__ b2, const float* __restrict__ loss,
                       float* __restrict__ out) {
    int lane = threadIdx.x;
    float w1[DH];
    #pragma unroll
    for (int k = 0; k < DH; ++k) w1[k] = W1[lane * DH + k];
    float bb = b1[lane], w2 = W2[lane];
    for (int g = 0; g < BATCH; ++g) {
        float gh = g_h[g * DH + lane];
        float a0 = 0.f, a1 = 0.f;
        #pragma unroll
        for (int k = 0; k < DH; k += 2) {
            a0 = fmaf(w1[k], bcast(gh, k), a0);
            a1 = fmaf(w1[k + 1], bcast(gh, k + 1), a1);
        }
        float t = gelu_f(a0 + a1 + bb);
        float p = wave_sum(t * w2);
        if (lane == 0) out[OUT_PREDS + g] = p + b2[0];
    }
    if (lane == 0) out[OUT_SAE] = (loss[0] + loss[1]) * (1.0f / ((float)NNODES * (float)DH));
}

extern "C" void kernel_launch(void* const* d_in, const int* in_sizes, int n_in,
                              void* d_out, int out_size, void* d_ws, size_t ws_size,
                              hipStream_t stream) {
    const float* x    = (const float*)d_in[0];
    const int* src    = (const int*)d_in[1];
    const int* dst    = (const int*)d_in[2];
    const float* encW = (const float*)d_in[3];
    const float* encB = (const float*)d_in[4];
    const float* gemb = (const float*)d_in[5];
    const float* ginW = (const float*)d_in[6];
    const float* bnw  = (const float*)d_in[7];
    const float* bnb  = (const float*)d_in[8];
    const float* keyW = (const float*)d_in[9];
    const float* keyB = (const float*)d_in[10];
    const float* qw   = (const float*)d_in[11];
    const float* valW = (const float*)d_in[12];
    const float* valB = (const float*)d_in[13];
    const float* saeEncW = (const float*)d_in[14];
    const float* saeEncB = (const float*)d_in[15];
    const float* saeDecW = (const float*)d_in[16];
    const float* saeDecB = (const float*)d_in[17];
    const float* pW1  = (const float*)d_in[18];
    const float* pb1  = (const float*)d_in[19];
    const float* pW2  = (const float*)d_in[20];
    const float* pb2  = (const float*)d_in[21];

    float* out = (float*)d_out;
    float* ws = (float*)d_ws;

    /* ws layout */
    int*   counts  = (int*)ws;                     /* NNODES */
    float* stats   = ws + NNODES;                  /* 128 */
    float* g_h     = stats + 128;                  /* 512 */
    float* loss    = g_h + 512;                    /* 2 */
    float* bnp     = loss + 2;                     /* 256: sc, sh, KQ, qb */
    int*   offsets = (int*)(bnp + 256);            /* NNODES */
    int*   cursor  = offsets + NNODES;             /* NNODES */
    unsigned short* csr = (unsigned short*)(cursor + NNODES); /* NEDGES u16 */
    int*   bsum    = (int*)(csr + NEDGES);         /* 256 */
    int*   boff    = bsum + 256;                   /* 256 */
    float* h2      = (float*)(boff + 256);         /* NDH */

    float* h    = out + OUT_DEC;   /* encoder output lives in dec region until k_sae */
    float* wout = out + OUT_W;

    /* zero counts + stats + g_h + loss */
    hipMemsetAsync(d_ws, 0, (size_t)(NNODES + 642) * sizeof(float), stream);

    k_encoder<<<2048, 256, 0, stream>>>(x, encW, encB, gemb, h);
    k_hist<<<2048, 256, 0, stream>>>(dst, counts);
    k_scan1<<<NSBLK, 256, 0, stream>>>(counts, bsum);
    k_scan2<<<1, 256, 0, stream>>>(bsum, boff);
    k_scan3<<<NSBLK, 256, 0, stream>>>(counts, boff, offsets, cursor);
    k_scatter<<<2048, 256, 0, stream>>>(src, dst, cursor, csr);
    k_aggin<<<2048, 256, 0, stream>>>(h, offsets, counts, csr, ginW, h2, stats);
    k_bnparams<<<1, 64, 0, stream>>>(stats, bnw, bnb, keyW, keyB, qw, bnp);
    k_attn<<<2048, 256, 0, stream>>>(h2, bnp, valW, valB, wout);
    k_sae<<<2048, 256, 0, stream>>>(h2, saeEncW, saeEncB, saeDecW, saeDecB, wout, h, g_h, loss);
    k_pred<<<1, 64, 0, stream>>>(g_h, pW1, pb1, pW2, pb2, loss, out);
}